// Round 8
// baseline (387.064 us; speedup 1.0000x reference)
//
#include <hip/hip_runtime.h>
#include <hip/hip_fp16.h>

#define N_NODES 100000
#define N_EDGES 3200000
#define BUCKET_NODES 128
#define NB 782            // fine buckets (128 dst nodes each)
#define NBC 98            // coarse buckets (1024 dst nodes each) = ceil(N/1024)
#define CHA 1024          // pass-A chunk (3125 blocks, exact)
#define CHB 1024          // pass-B chunk (3125 blocks, exact)
#define FS_CAP 4608       // finesort LDS capacity (mean bucket 4096, +8 sigma)

__device__ __forceinline__ unsigned short f2bf(float f) {
    unsigned u = __float_as_uint(f);
    unsigned r = (u + 0x7FFFu + ((u >> 16) & 1u)) >> 16;   // RNE
    return (unsigned short)r;
}
__device__ __forceinline__ float bf2f(unsigned short h) {
    return __uint_as_float(((unsigned)h) << 16);
}

// ---------------------------------------------------------------------------
// Kernel A: feat(bf16) = node_feat @ Wfc.T, el/er = sum(feat*attn, -1)
// ---------------------------------------------------------------------------
__global__ __launch_bounds__(256) void node_proj(
    const float* __restrict__ node_feat,
    const float* __restrict__ Wfc,
    const float* __restrict__ attn_l,
    const float* __restrict__ attn_r,
    unsigned short* __restrict__ featb,
    float* __restrict__ el,
    float* __restrict__ er)
{
    __shared__ float T2[32 * 64 * 4];   // T2[(k4*64 + j)*4 + kk] = Wfc[j*128 + k4*4+kk]
    const int tid = threadIdx.x;
    for (int i = tid; i < 64 * 128; i += 256) {
        int j = i >> 7, k = i & 127;
        T2[((k >> 2) * 64 + j) * 4 + (k & 3)] = Wfc[i];
    }
    __syncthreads();

    const int lane = tid & 63;
    const float al = attn_l[lane];
    const float ar = attn_r[lane];
    const int gw = blockIdx.x * 4 + (tid >> 6);
    const int nw = gridDim.x * 4;
    const float4* __restrict__ T2v = (const float4*)T2;

    for (int g = gw; g * 4 < N_NODES; g += nw) {
        const int n0 = g * 4;
        const float4* __restrict__ x0 = (const float4*)(node_feat + (size_t)(n0 + 0) * 128);
        const float4* __restrict__ x1 = (const float4*)(node_feat + (size_t)(n0 + 1) * 128);
        const float4* __restrict__ x2 = (const float4*)(node_feat + (size_t)(n0 + 2) * 128);
        const float4* __restrict__ x3 = (const float4*)(node_feat + (size_t)(n0 + 3) * 128);

        float acc0 = 0.f, acc1 = 0.f, acc2 = 0.f, acc3 = 0.f;
        #pragma unroll 8
        for (int k4 = 0; k4 < 32; ++k4) {
            const float4 v0 = x0[k4], v1 = x1[k4], v2 = x2[k4], v3 = x3[k4];
            const float4 w = T2v[k4 * 64 + lane];
            acc0 = fmaf(v0.x, w.x, acc0); acc0 = fmaf(v0.y, w.y, acc0);
            acc0 = fmaf(v0.z, w.z, acc0); acc0 = fmaf(v0.w, w.w, acc0);
            acc1 = fmaf(v1.x, w.x, acc1); acc1 = fmaf(v1.y, w.y, acc1);
            acc1 = fmaf(v1.z, w.z, acc1); acc1 = fmaf(v1.w, w.w, acc1);
            acc2 = fmaf(v2.x, w.x, acc2); acc2 = fmaf(v2.y, w.y, acc2);
            acc2 = fmaf(v2.z, w.z, acc2); acc2 = fmaf(v2.w, w.w, acc2);
            acc3 = fmaf(v3.x, w.x, acc3); acc3 = fmaf(v3.y, w.y, acc3);
            acc3 = fmaf(v3.z, w.z, acc3); acc3 = fmaf(v3.w, w.w, acc3);
        }

        featb[(size_t)(n0 + 0) * 64 + lane] = f2bf(acc0);
        featb[(size_t)(n0 + 1) * 64 + lane] = f2bf(acc1);
        featb[(size_t)(n0 + 2) * 64 + lane] = f2bf(acc2);
        featb[(size_t)(n0 + 3) * 64 + lane] = f2bf(acc3);

        const float accs[4] = {acc0, acc1, acc2, acc3};
        #pragma unroll
        for (int i = 0; i < 4; ++i) {
            float vl = accs[i] * al;
            float vr = accs[i] * ar;
            #pragma unroll
            for (int off = 8; off >= 1; off >>= 1) {
                vl += __shfl_xor(vl, off);
                vr += __shfl_xor(vr, off);
            }
            if ((lane & 15) == 0) {
                el[(size_t)(n0 + i) * 4 + (lane >> 4)] = vl;
                er[(size_t)(n0 + i) * 4 + (lane >> 4)] = vr;
            }
        }
    }
}

// ---------------------------------------------------------------------------
// Fine-bucket histogram (782): LDS-aggregated
// ---------------------------------------------------------------------------
__global__ __launch_bounds__(256) void bhist(const int* __restrict__ dst,
                                             int* __restrict__ totals)
{
    __shared__ int h[NB];
    for (int i = threadIdx.x; i < NB; i += 256) h[i] = 0;
    __syncthreads();
    const int stride = gridDim.x * 256;
    for (int e = blockIdx.x * 256 + threadIdx.x; e < N_EDGES; e += stride)
        atomicAdd(&h[dst[e] >> 7], 1);
    __syncthreads();
    for (int i = threadIdx.x; i < NB; i += 256)
        if (h[i]) atomicAdd(&totals[i], h[i]);
}

// ---------------------------------------------------------------------------
// Scan: fine base/cursor (782) + coarse base/cursor (98) derived from groups
// of 8 fine buckets. Single wave; LDS copy for the coarse derivation.
// ---------------------------------------------------------------------------
__global__ __launch_bounds__(64) void bscan(const int* __restrict__ totals,
                                            int* __restrict__ base,
                                            int* __restrict__ fcursor,
                                            int* __restrict__ cbase,
                                            int* __restrict__ ccursor)
{
    __shared__ int sb[NB + 1];
    const int lane = threadIdx.x;
    int carry = 0;
    for (int ch = 0; ch < NB; ch += 64) {
        const int idx = ch + lane;
        const int v = (idx < NB) ? totals[idx] : 0;
        int x = v;
        #pragma unroll
        for (int off = 1; off < 64; off <<= 1) {
            int y = __shfl_up(x, off);
            if (lane >= off) x += y;
        }
        const int excl = x - v + carry;
        if (idx < NB) { base[idx] = excl; fcursor[idx] = excl; sb[idx] = excl; }
        carry += __shfl(x, 63);
    }
    if (lane == 0) { base[NB] = carry; sb[NB] = carry; }
    // same-wave LDS ops are in program order; sb fully written above
    for (int cb = lane; cb <= NBC; cb += 64) {
        const int idx = min(cb * 8, NB);
        cbase[cb] = sb[idx];
        if (cb < NBC) ccursor[cb] = sb[idx];
    }
}

// ---------------------------------------------------------------------------
// Pass A: scatter into 98 coarse buckets. Payload 8 B:
//   [src:0..16 | dst_low10:17..26 | eid:27..48].  No sigma here.
// Output lives in d_out (dead before aggregate rewrites it).
// ---------------------------------------------------------------------------
__global__ __launch_bounds__(256) void passA(
    const int* __restrict__ src,
    const int* __restrict__ dst,
    int* __restrict__ ccursor,
    unsigned long long* __restrict__ wA)
{
    __shared__ int lbase[NBC];
    __shared__ int lcnt[NBC];
    const int tid = threadIdx.x;
    if (tid < NBC) lcnt[tid] = 0;
    __syncthreads();
    const int e0 = blockIdx.x * CHA;
    for (int i = tid; i < CHA; i += 256)
        atomicAdd(&lcnt[dst[e0 + i] >> 10], 1);
    __syncthreads();
    if (tid < NBC) {
        const int c = lcnt[tid];
        lbase[tid] = c ? atomicAdd(&ccursor[tid], c) : 0;
        lcnt[tid] = 0;
    }
    __syncthreads();
    for (int i = tid; i < CHA; i += 256) {
        const int d = dst[e0 + i];
        const int cb = d >> 10;
        const int r = atomicAdd(&lcnt[cb], 1);
        wA[lbase[cb] + r] = (unsigned long long)(unsigned)src[e0 + i]
                          | ((unsigned long long)(unsigned)(d & 1023) << 17)
                          | ((unsigned long long)(unsigned)(e0 + i) << 27);
    }
}

// ---------------------------------------------------------------------------
// Pass B: refine each coarse slice into 8 fine buckets (runs ~64 edges =
// full-line writes) AND compute the sigma-path. Coarse id recovered from
// position via binary search over coarse boundaries. Payload out: 12 B
// {src | dl<<17, ee01 fp16x2, ee23 fp16x2} — same format finesort/aggregate use.
// ---------------------------------------------------------------------------
__global__ __launch_bounds__(256) void passB(
    const float* __restrict__ edge_feat,
    const float* __restrict__ We,
    const float* __restrict__ el,
    const float* __restrict__ er,
    const int* __restrict__ cbase,
    int* __restrict__ fcursor,
    const unsigned long long* __restrict__ wA,
    uint3* __restrict__ wB)
{
    __shared__ int lbase[NB];
    __shared__ int lcnt[NB];
    __shared__ int lcb[NBC + 1];
    __shared__ unsigned long long sx[CHB];
    __shared__ unsigned short sfid[CHB];
    const int tid = threadIdx.x;
    for (int i = tid; i < NB; i += 256) lcnt[i] = 0;
    if (tid < NBC + 1) lcb[tid] = cbase[tid];
    __syncthreads();

    const int p0 = blockIdx.x * CHB;
    for (int i = tid; i < CHB; i += 256) {
        const unsigned long long x = wA[p0 + i];
        sx[i] = x;
        const int pos = p0 + i;
        int lo = 0, hi = NBC;           // invariant: lcb[lo] <= pos < lcb[hi]
        while (lo + 1 < hi) {
            const int mid = (lo + hi) >> 1;
            if (lcb[mid] <= pos) lo = mid; else hi = mid;
        }
        const int dst10 = (int)((x >> 17) & 1023u);
        const int fid = lo * 8 + (dst10 >> 7);
        sfid[i] = (unsigned short)fid;
        atomicAdd(&lcnt[fid], 1);
    }
    __syncthreads();
    for (int b = tid; b < NB; b += 256) {
        const int c = lcnt[b];
        lbase[b] = c ? atomicAdd(&fcursor[b], c) : 0;
        lcnt[b] = 0;
    }
    __syncthreads();

    const float4 W0 = ((const float4*)We)[0];
    const float4 W1 = ((const float4*)We)[1];
    const float4 W2 = ((const float4*)We)[2];
    const float4 W3 = ((const float4*)We)[3];

    for (int i = tid; i < CHB; i += 256) {
        const unsigned long long x = sx[i];
        const int fid = sfid[i];
        const int r = atomicAdd(&lcnt[fid], 1);
        const int pos = lbase[fid] + r;

        const int s = (int)(x & 0x1FFFFull);
        const int dst10 = (int)((x >> 17) & 1023u);
        const int d = ((fid >> 3) << 10) | dst10;
        const int eid = (int)(x >> 27);

        const float4 ef = ((const float4*)edge_feat)[eid];
        const float4 l4 = ((const float4*)el)[s];
        const float4 r4 = ((const float4*)er)[d];

        float t0 = l4.x + r4.x; t0 = t0 > 0.f ? t0 : 0.2f * t0;
        float t1 = l4.y + r4.y; t1 = t1 > 0.f ? t1 : 0.2f * t1;
        float t2 = l4.z + r4.z; t2 = t2 > 0.f ? t2 : 0.2f * t2;
        float t3 = l4.w + r4.w; t3 = t3 > 0.f ? t3 : 0.2f * t3;

        const float ee0 = __expf(t0 * (W0.x * ef.x + W0.y * ef.y + W0.z * ef.z + W0.w * ef.w));
        const float ee1 = __expf(t1 * (W1.x * ef.x + W1.y * ef.y + W1.z * ef.z + W1.w * ef.w));
        const float ee2 = __expf(t2 * (W2.x * ef.x + W2.y * ef.y + W2.z * ef.z + W2.w * ef.w));
        const float ee3 = __expf(t3 * (W3.x * ef.x + W3.y * ef.y + W3.z * ef.z + W3.w * ef.w));

        const unsigned h0 = __half_as_ushort(__float2half_rn(ee0));
        const unsigned h1 = __half_as_ushort(__float2half_rn(ee1));
        const unsigned h2 = __half_as_ushort(__float2half_rn(ee2));
        const unsigned h3 = __half_as_ushort(__float2half_rn(ee3));

        wB[pos] = make_uint3((unsigned)s | ((unsigned)(d & (BUCKET_NODES - 1)) << 17),
                             h0 | (h1 << 16), h2 | (h3 << 16));
    }
}

// ---------------------------------------------------------------------------
// Finesort: one block per fine bucket. Counting-sort of 12 B payload by
// dst-local IN PLACE, emit exact per-node CSR offsets. All atomics LDS.
// ---------------------------------------------------------------------------
__global__ __launch_bounds__(256) void finesort(
    const int* __restrict__ base,
    uint3* __restrict__ wP,
    int* __restrict__ node_off)
{
    __shared__ uint3 sP[FS_CAP];          // 54 KB
    __shared__ int hist[BUCKET_NODES];
    __shared__ int cur[BUCKET_NODES];
    const int b = blockIdx.x;
    const int s = base[b];
    int cnt = base[b + 1] - s;
    if (cnt > FS_CAP) cnt = FS_CAP;   // unreachable for this dataset; safety
    const int tid = threadIdx.x;
    if (tid < BUCKET_NODES) hist[tid] = 0;
    __syncthreads();
    for (int i = tid; i < cnt; i += 256) {
        const uint3 p = wP[s + i];
        sP[i] = p;
        atomicAdd(&hist[(p.x >> 17) & (BUCKET_NODES - 1)], 1);
    }
    __syncthreads();
    if (tid < 64) {
        int carry = 0;
        for (int ch = 0; ch < BUCKET_NODES; ch += 64) {
            const int v = hist[ch + tid];
            int x = v;
            #pragma unroll
            for (int off = 1; off < 64; off <<= 1) {
                int y = __shfl_up(x, off);
                if (tid >= off) x += y;
            }
            const int excl = x - v + carry;
            cur[ch + tid] = excl;
            const int node = b * BUCKET_NODES + ch + tid;
            if (node < N_NODES) node_off[node] = s + excl;
            carry += __shfl(x, 63);
        }
        if (tid == 0 && b == NB - 1) node_off[N_NODES] = N_EDGES;
    }
    __syncthreads();
    for (int i = tid; i < cnt; i += 256) {
        const uint3 p = sP[i];
        const int dl = (p.x >> 17) & (BUCKET_NODES - 1);
        const int r = atomicAdd(&cur[dl], 1);
        wP[s + r] = p;
    }
}

// ---------------------------------------------------------------------------
// Aggregate: one wave per dst node. Phase 1: each lane decodes its OWN
// edge's ee4 into LDS + register ssum. Phase 2 per edge: 2 ds_read + featb
// gather + 1 fma.
// ---------------------------------------------------------------------------
__global__ __launch_bounds__(256) void aggregate(
    const int* __restrict__ node_off,
    const uint3* __restrict__ wP,
    const unsigned short* __restrict__ featb,
    float* __restrict__ rst)
{
    __shared__ float lee[4][64][4];   // [wave][edge][c]   16 KB
    __shared__ int   lsi[4][64];      //                    1 KB
    const int tid = threadIdx.x;
    const int node = (int)((blockIdx.x * 256 + tid) >> 6);
    const int lane = tid & 63;
    const int w = tid >> 6;
    if (node >= N_NODES) return;
    const int c = lane >> 4;

    const int start = node_off[node];
    const int end = node_off[node + 1];

    float acc = 0.f;
    float s0 = 0.f, s1 = 0.f, s2 = 0.f, s3 = 0.f;

    for (int bat = start; bat < end; bat += 64) {
        const int n = min(64, end - bat);
        if (lane < n) {
            const uint3 p = wP[bat + lane];
            const float e0 = __half2float(__ushort_as_half((unsigned short)(p.y & 0xffffu)));
            const float e1 = __half2float(__ushort_as_half((unsigned short)(p.y >> 16)));
            const float e2 = __half2float(__ushort_as_half((unsigned short)(p.z & 0xffffu)));
            const float e3 = __half2float(__ushort_as_half((unsigned short)(p.z >> 16)));
            lsi[w][lane] = (int)(p.x & 0x1FFFFu);
            float4 v = make_float4(e0, e1, e2, e3);
            *(float4*)&lee[w][lane][0] = v;
            s0 += e0; s1 += e1; s2 += e2; s3 += e3;
        }
        __builtin_amdgcn_wave_barrier();   // keep LDS write->read in program order
        for (int i = 0; i < n; ++i) {
            const int si = lsi[w][i];
            const float eec = lee[w][i][c];
            const float fv = bf2f(featb[(size_t)si * 64 + lane]);
            acc = fmaf(eec, fv, acc);
        }
        __builtin_amdgcn_wave_barrier();   // WAR: next batch overwrites lee
    }

    #pragma unroll
    for (int off = 32; off >= 1; off >>= 1) {
        s0 += __shfl_xor(s0, off);
        s1 += __shfl_xor(s1, off);
        s2 += __shfl_xor(s2, off);
        s3 += __shfl_xor(s3, off);
    }
    const float ssum = (c == 0) ? s0 : ((c == 1) ? s1 : ((c == 2) ? s2 : s3));
    rst[(size_t)node * 64 + lane] = (end > start) ? acc / ssum : 0.f;
}

// ---------------------------------------------------------------------------
extern "C" void kernel_launch(void* const* d_in, const int* in_sizes, int n_in,
                              void* d_out, int out_size, void* d_ws, size_t ws_size,
                              hipStream_t stream)
{
    const float* node_feat = (const float*)d_in[0];
    const float* edge_feat = (const float*)d_in[1];
    const int*   src       = (const int*)d_in[2];
    const int*   dst       = (const int*)d_in[3];
    const float* Wfc       = (const float*)d_in[4];
    const float* We        = (const float*)d_in[5];
    const float* attn_l    = (const float*)d_in[6];
    const float* attn_r    = (const float*)d_in[7];
    float* rst = (float*)d_out;

    char* ws = (char*)d_ws;
    unsigned short* featb = (unsigned short*)(ws);        // 12,800,000 B
    float* el      = (float*)(ws + 12800000);             //  1,600,000 B
    float* er      = (float*)(ws + 14400000);             //  1,600,000 B
    int*   totals  = (int*)  (ws + 16000000);             //  3,128 B (pad 4K)
    int*   base    = (int*)  (ws + 16004096);             //  3,132 B (pad 4K)
    int*   fcursor = (int*)  (ws + 16008192);             //  3,128 B (pad 4K)
    int*   cbase   = (int*)  (ws + 16012288);             //    396 B (pad 4K)
    int*   ccursor = (int*)  (ws + 16016384);             //    392 B (pad 4K)
    int*   node_off= (int*)  (ws + 16020480);             //    400,004 B (pad)
    uint3* wB      = (uint3*)(ws + 16424960);             // 38,400,000 B
                                                          // total ~54.8 MB
    // d_out doubles as the pass-A payload buffer (25.6 MB, exactly out_size);
    // it is fully dead before aggregate rewrites every element of rst.
    unsigned long long* wA = (unsigned long long*)d_out;

    hipMemsetAsync(totals, 0, NB * sizeof(int), stream);

    node_proj<<<1250, 256, 0, stream>>>(node_feat, Wfc, attn_l, attn_r, featb, el, er);
    bhist<<<512, 256, 0, stream>>>(dst, totals);
    bscan<<<1, 64, 0, stream>>>(totals, base, fcursor, cbase, ccursor);
    passA<<<N_EDGES / CHA, 256, 0, stream>>>(src, dst, ccursor, wA);
    passB<<<N_EDGES / CHB, 256, 0, stream>>>(edge_feat, We, el, er, cbase, fcursor, wA, wB);
    finesort<<<NB, 256, 0, stream>>>(base, wB, node_off);
    aggregate<<<(N_NODES * 64 + 255) / 256, 256, 0, stream>>>(node_off, wB, featb, rst);
}

// Round 9
// 311.312 us; speedup vs baseline: 1.2433x; 1.2433x over previous
//
#include <hip/hip_runtime.h>
#include <hip/hip_fp16.h>

#define N_NODES 100000
#define N_EDGES 3200000
#define BUCKET_NODES 128
#define NB 782            // fine buckets (128 dst nodes each)
#define NBC 98            // coarse buckets (1024 dst nodes each) = ceil(N/1024)
#define CHA 4096          // pass-A chunk
#define NPA 782           // ceil(N_EDGES / CHA)
#define CHB 2048          // pass-B chunk
#define NPB 1563          // ceil(N_EDGES / CHB)
#define FS_CAP 4608       // finesort LDS capacity (mean bucket 4096, +8 sigma)
#define NGROUPS 3125      // node_proj groups of 32 nodes (exact: 100000/32)

__device__ __forceinline__ unsigned short f2bf(float f) {
    unsigned u = __float_as_uint(f);
    unsigned r = (u + 0x7FFFu + ((u >> 16) & 1u)) >> 16;   // RNE
    return (unsigned short)r;
}
__device__ __forceinline__ float bf2f(unsigned short h) {
    return __uint_as_float(((unsigned)h) << 16);
}

// ---------------------------------------------------------------------------
// Kernel A (v2): feat(bf16) = node_feat @ Wfc.T, el/er = sum(feat*attn, -1)
// Fix vs v1: node inputs are STAGED via coalesced loads (1 KB/instr) into
// LDS, then consumed as same-address broadcasts. v1 issued wave-uniform
// 16 B loads (1/64 load efficiency) and was latency-bound at 137 us.
// Per wave-iteration: 8 nodes. LDS: 32 KB weights + 16 KB staging = 48 KB.
// ---------------------------------------------------------------------------
__global__ __launch_bounds__(256) void node_proj(
    const float* __restrict__ node_feat,
    const float* __restrict__ Wfc,
    const float* __restrict__ attn_l,
    const float* __restrict__ attn_r,
    unsigned short* __restrict__ featb,
    float* __restrict__ el,
    float* __restrict__ er)
{
    __shared__ float T2[32 * 64 * 4];   // T2[(k4*64 + j)*4 + kk] = Wfc[j*128 + k4*4+kk]
    __shared__ float X[4][8][128];      // [wave][node][k]  16 KB
    const int tid = threadIdx.x;
    for (int i = tid; i < 64 * 128; i += 256) {
        int j = i >> 7, k = i & 127;
        T2[((k >> 2) * 64 + j) * 4 + (k & 3)] = Wfc[i];
    }
    __syncthreads();

    const int lane = tid & 63;
    const int w = tid >> 6;
    const float al = attn_l[lane];
    const float ar = attn_r[lane];
    const float4* __restrict__ T2v = (const float4*)T2;

    for (int g = blockIdx.x; g < NGROUPS; g += gridDim.x) {
        const int n0 = g * 32 + w * 8;          // this wave's 8 nodes
        const float4* __restrict__ gsrc = (const float4*)(node_feat + (size_t)n0 * 128);

        // stage 8 nodes x 128 floats: 4 coalesced float4 loads per lane
        #pragma unroll
        for (int t = 0; t < 4; ++t) {
            const float4 v = gsrc[t * 64 + lane];
            const int f = t * 256 + lane * 4;   // flat float index
            *(float4*)&X[w][f >> 7][f & 127] = v;
        }
        __builtin_amdgcn_wave_barrier();        // wave-local LDS RAW ordering

        float acc[8] = {0.f, 0.f, 0.f, 0.f, 0.f, 0.f, 0.f, 0.f};
        #pragma unroll 4
        for (int k4 = 0; k4 < 32; ++k4) {
            const float4 wv = T2v[k4 * 64 + lane];
            #pragma unroll
            for (int n = 0; n < 8; ++n) {
                const float4 xv = *(const float4*)&X[w][n][k4 * 4];  // broadcast
                acc[n] = fmaf(xv.x, wv.x, acc[n]);
                acc[n] = fmaf(xv.y, wv.y, acc[n]);
                acc[n] = fmaf(xv.z, wv.z, acc[n]);
                acc[n] = fmaf(xv.w, wv.w, acc[n]);
            }
        }

        #pragma unroll
        for (int n = 0; n < 8; ++n)
            featb[(size_t)(n0 + n) * 64 + lane] = f2bf(acc[n]);

        #pragma unroll
        for (int n = 0; n < 8; ++n) {
            float vl = acc[n] * al;
            float vr = acc[n] * ar;
            #pragma unroll
            for (int off = 8; off >= 1; off >>= 1) {
                vl += __shfl_xor(vl, off);
                vr += __shfl_xor(vr, off);
            }
            if ((lane & 15) == 0) {
                el[(size_t)(n0 + n) * 4 + (lane >> 4)] = vl;
                er[(size_t)(n0 + n) * 4 + (lane >> 4)] = vr;
            }
        }
        __builtin_amdgcn_wave_barrier();        // WAR before next stage
    }
}

// ---------------------------------------------------------------------------
// Fine-bucket histogram (782): LDS-aggregated
// ---------------------------------------------------------------------------
__global__ __launch_bounds__(256) void bhist(const int* __restrict__ dst,
                                             int* __restrict__ totals)
{
    __shared__ int h[NB];
    for (int i = threadIdx.x; i < NB; i += 256) h[i] = 0;
    __syncthreads();
    const int stride = gridDim.x * 256;
    for (int e = blockIdx.x * 256 + threadIdx.x; e < N_EDGES; e += stride)
        atomicAdd(&h[dst[e] >> 7], 1);
    __syncthreads();
    for (int i = threadIdx.x; i < NB; i += 256)
        if (h[i]) atomicAdd(&totals[i], h[i]);
}

// ---------------------------------------------------------------------------
// Scan: fine base/cursor (782) + coarse base/cursor (98)
// ---------------------------------------------------------------------------
__global__ __launch_bounds__(64) void bscan(const int* __restrict__ totals,
                                            int* __restrict__ base,
                                            int* __restrict__ fcursor,
                                            int* __restrict__ cbase,
                                            int* __restrict__ ccursor)
{
    __shared__ int sb[NB + 1];
    const int lane = threadIdx.x;
    int carry = 0;
    for (int ch = 0; ch < NB; ch += 64) {
        const int idx = ch + lane;
        const int v = (idx < NB) ? totals[idx] : 0;
        int x = v;
        #pragma unroll
        for (int off = 1; off < 64; off <<= 1) {
            int y = __shfl_up(x, off);
            if (lane >= off) x += y;
        }
        const int excl = x - v + carry;
        if (idx < NB) { base[idx] = excl; fcursor[idx] = excl; sb[idx] = excl; }
        carry += __shfl(x, 63);
    }
    if (lane == 0) { base[NB] = carry; sb[NB] = carry; }
    for (int cb = lane; cb <= NBC; cb += 64) {
        const int idx = min(cb * 8, NB);
        cbase[cb] = sb[idx];
        if (cb < NBC) ccursor[cb] = sb[idx];
    }
}

// ---------------------------------------------------------------------------
// Pass A: scatter into 98 coarse buckets. Payload 8 B:
//   [src:0..16 | dst_low10:17..26 | eid:27..48].
// CHA=4096 -> runs ~42 edges (334 B) -> few partial-line RFOs.
// ---------------------------------------------------------------------------
__global__ __launch_bounds__(256) void passA(
    const int* __restrict__ src,
    const int* __restrict__ dst,
    int* __restrict__ ccursor,
    unsigned long long* __restrict__ wA)
{
    __shared__ int lbase[NBC];
    __shared__ int lcnt[NBC];
    const int tid = threadIdx.x;
    if (tid < NBC) lcnt[tid] = 0;
    __syncthreads();
    const int e0 = blockIdx.x * CHA;
    const int n = min(CHA, N_EDGES - e0);
    for (int i = tid; i < n; i += 256)
        atomicAdd(&lcnt[dst[e0 + i] >> 10], 1);
    __syncthreads();
    if (tid < NBC) {
        const int c = lcnt[tid];
        lbase[tid] = c ? atomicAdd(&ccursor[tid], c) : 0;
        lcnt[tid] = 0;
    }
    __syncthreads();
    for (int i = tid; i < n; i += 256) {
        const int d = dst[e0 + i];
        const int cb = d >> 10;
        const int r = atomicAdd(&lcnt[cb], 1);
        wA[lbase[cb] + r] = (unsigned long long)(unsigned)src[e0 + i]
                          | ((unsigned long long)(unsigned)(d & 1023) << 17)
                          | ((unsigned long long)(unsigned)(e0 + i) << 27);
    }
}

// ---------------------------------------------------------------------------
// Pass B: refine each coarse slice into 8 fine buckets (runs ~128 edges)
// AND compute the sigma-path. Payload out: 12 B {src|dl<<17, ee01, ee23}.
// ---------------------------------------------------------------------------
__global__ __launch_bounds__(256) void passB(
    const float* __restrict__ edge_feat,
    const float* __restrict__ We,
    const float* __restrict__ el,
    const float* __restrict__ er,
    const int* __restrict__ cbase,
    int* __restrict__ fcursor,
    const unsigned long long* __restrict__ wA,
    uint3* __restrict__ wB)
{
    __shared__ int lbase[NB];
    __shared__ int lcnt[NB];
    __shared__ int lcb[NBC + 1];
    __shared__ unsigned long long sx[CHB];
    __shared__ unsigned short sfid[CHB];
    const int tid = threadIdx.x;
    for (int i = tid; i < NB; i += 256) lcnt[i] = 0;
    if (tid < NBC + 1) lcb[tid] = cbase[tid];
    __syncthreads();

    const int p0 = blockIdx.x * CHB;
    const int n = min(CHB, N_EDGES - p0);
    for (int i = tid; i < n; i += 256) {
        const unsigned long long x = wA[p0 + i];
        sx[i] = x;
        const int pos = p0 + i;
        int lo = 0, hi = NBC;           // invariant: lcb[lo] <= pos < lcb[hi]
        while (lo + 1 < hi) {
            const int mid = (lo + hi) >> 1;
            if (lcb[mid] <= pos) lo = mid; else hi = mid;
        }
        const int dst10 = (int)((x >> 17) & 1023u);
        const int fid = lo * 8 + (dst10 >> 7);
        sfid[i] = (unsigned short)fid;
        atomicAdd(&lcnt[fid], 1);
    }
    __syncthreads();
    for (int b = tid; b < NB; b += 256) {
        const int c = lcnt[b];
        lbase[b] = c ? atomicAdd(&fcursor[b], c) : 0;
        lcnt[b] = 0;
    }
    __syncthreads();

    const float4 W0 = ((const float4*)We)[0];
    const float4 W1 = ((const float4*)We)[1];
    const float4 W2 = ((const float4*)We)[2];
    const float4 W3 = ((const float4*)We)[3];

    for (int i = tid; i < n; i += 256) {
        const unsigned long long x = sx[i];
        const int fid = sfid[i];
        const int r = atomicAdd(&lcnt[fid], 1);
        const int pos = lbase[fid] + r;

        const int s = (int)(x & 0x1FFFFull);
        const int dst10 = (int)((x >> 17) & 1023u);
        const int d = ((fid >> 3) << 10) | dst10;
        const int eid = (int)(x >> 27);

        const float4 ef = ((const float4*)edge_feat)[eid];
        const float4 l4 = ((const float4*)el)[s];
        const float4 r4 = ((const float4*)er)[d];

        float t0 = l4.x + r4.x; t0 = t0 > 0.f ? t0 : 0.2f * t0;
        float t1 = l4.y + r4.y; t1 = t1 > 0.f ? t1 : 0.2f * t1;
        float t2 = l4.z + r4.z; t2 = t2 > 0.f ? t2 : 0.2f * t2;
        float t3 = l4.w + r4.w; t3 = t3 > 0.f ? t3 : 0.2f * t3;

        const float ee0 = __expf(t0 * (W0.x * ef.x + W0.y * ef.y + W0.z * ef.z + W0.w * ef.w));
        const float ee1 = __expf(t1 * (W1.x * ef.x + W1.y * ef.y + W1.z * ef.z + W1.w * ef.w));
        const float ee2 = __expf(t2 * (W2.x * ef.x + W2.y * ef.y + W2.z * ef.z + W2.w * ef.w));
        const float ee3 = __expf(t3 * (W3.x * ef.x + W3.y * ef.y + W3.z * ef.z + W3.w * ef.w));

        const unsigned h0 = __half_as_ushort(__float2half_rn(ee0));
        const unsigned h1 = __half_as_ushort(__float2half_rn(ee1));
        const unsigned h2 = __half_as_ushort(__float2half_rn(ee2));
        const unsigned h3 = __half_as_ushort(__float2half_rn(ee3));

        wB[pos] = make_uint3((unsigned)s | ((unsigned)(d & (BUCKET_NODES - 1)) << 17),
                             h0 | (h1 << 16), h2 | (h3 << 16));
    }
}

// ---------------------------------------------------------------------------
// Finesort: one block per fine bucket. Counting-sort of 12 B payload by
// dst-local IN PLACE, emit exact per-node CSR offsets. All atomics LDS.
// ---------------------------------------------------------------------------
__global__ __launch_bounds__(256) void finesort(
    const int* __restrict__ base,
    uint3* __restrict__ wP,
    int* __restrict__ node_off)
{
    __shared__ uint3 sP[FS_CAP];          // 54 KB
    __shared__ int hist[BUCKET_NODES];
    __shared__ int cur[BUCKET_NODES];
    const int b = blockIdx.x;
    const int s = base[b];
    int cnt = base[b + 1] - s;
    if (cnt > FS_CAP) cnt = FS_CAP;   // unreachable for this dataset; safety
    const int tid = threadIdx.x;
    if (tid < BUCKET_NODES) hist[tid] = 0;
    __syncthreads();
    for (int i = tid; i < cnt; i += 256) {
        const uint3 p = wP[s + i];
        sP[i] = p;
        atomicAdd(&hist[(p.x >> 17) & (BUCKET_NODES - 1)], 1);
    }
    __syncthreads();
    if (tid < 64) {
        int carry = 0;
        for (int ch = 0; ch < BUCKET_NODES; ch += 64) {
            const int v = hist[ch + tid];
            int x = v;
            #pragma unroll
            for (int off = 1; off < 64; off <<= 1) {
                int y = __shfl_up(x, off);
                if (tid >= off) x += y;
            }
            const int excl = x - v + carry;
            cur[ch + tid] = excl;
            const int node = b * BUCKET_NODES + ch + tid;
            if (node < N_NODES) node_off[node] = s + excl;
            carry += __shfl(x, 63);
        }
        if (tid == 0 && b == NB - 1) node_off[N_NODES] = N_EDGES;
    }
    __syncthreads();
    for (int i = tid; i < cnt; i += 256) {
        const uint3 p = sP[i];
        const int dl = (p.x >> 17) & (BUCKET_NODES - 1);
        const int r = atomicAdd(&cur[dl], 1);
        wP[s + r] = p;
    }
}

// ---------------------------------------------------------------------------
// Aggregate: one wave per dst node. Phase 1: each lane decodes its OWN
// edge's ee4 into LDS + register ssum. Phase 2 per edge: 2 ds_read + featb
// gather + 1 fma.
// ---------------------------------------------------------------------------
__global__ __launch_bounds__(256) void aggregate(
    const int* __restrict__ node_off,
    const uint3* __restrict__ wP,
    const unsigned short* __restrict__ featb,
    float* __restrict__ rst)
{
    __shared__ float lee[4][64][4];   // [wave][edge][c]   16 KB
    __shared__ int   lsi[4][64];      //                    1 KB
    const int tid = threadIdx.x;
    const int node = (int)((blockIdx.x * 256 + tid) >> 6);
    const int lane = tid & 63;
    const int w = tid >> 6;
    if (node >= N_NODES) return;
    const int c = lane >> 4;

    const int start = node_off[node];
    const int end = node_off[node + 1];

    float acc = 0.f;
    float s0 = 0.f, s1 = 0.f, s2 = 0.f, s3 = 0.f;

    for (int bat = start; bat < end; bat += 64) {
        const int n = min(64, end - bat);
        if (lane < n) {
            const uint3 p = wP[bat + lane];
            const float e0 = __half2float(__ushort_as_half((unsigned short)(p.y & 0xffffu)));
            const float e1 = __half2float(__ushort_as_half((unsigned short)(p.y >> 16)));
            const float e2 = __half2float(__ushort_as_half((unsigned short)(p.z & 0xffffu)));
            const float e3 = __half2float(__ushort_as_half((unsigned short)(p.z >> 16)));
            lsi[w][lane] = (int)(p.x & 0x1FFFFu);
            float4 v = make_float4(e0, e1, e2, e3);
            *(float4*)&lee[w][lane][0] = v;
            s0 += e0; s1 += e1; s2 += e2; s3 += e3;
        }
        __builtin_amdgcn_wave_barrier();   // keep LDS write->read in program order
        for (int i = 0; i < n; ++i) {
            const int si = lsi[w][i];
            const float eec = lee[w][i][c];
            const float fv = bf2f(featb[(size_t)si * 64 + lane]);
            acc = fmaf(eec, fv, acc);
        }
        __builtin_amdgcn_wave_barrier();   // WAR: next batch overwrites lee
    }

    #pragma unroll
    for (int off = 32; off >= 1; off >>= 1) {
        s0 += __shfl_xor(s0, off);
        s1 += __shfl_xor(s1, off);
        s2 += __shfl_xor(s2, off);
        s3 += __shfl_xor(s3, off);
    }
    const float ssum = (c == 0) ? s0 : ((c == 1) ? s1 : ((c == 2) ? s2 : s3));
    rst[(size_t)node * 64 + lane] = (end > start) ? acc / ssum : 0.f;
}

// ---------------------------------------------------------------------------
extern "C" void kernel_launch(void* const* d_in, const int* in_sizes, int n_in,
                              void* d_out, int out_size, void* d_ws, size_t ws_size,
                              hipStream_t stream)
{
    const float* node_feat = (const float*)d_in[0];
    const float* edge_feat = (const float*)d_in[1];
    const int*   src       = (const int*)d_in[2];
    const int*   dst       = (const int*)d_in[3];
    const float* Wfc       = (const float*)d_in[4];
    const float* We        = (const float*)d_in[5];
    const float* attn_l    = (const float*)d_in[6];
    const float* attn_r    = (const float*)d_in[7];
    float* rst = (float*)d_out;

    char* ws = (char*)d_ws;
    unsigned short* featb = (unsigned short*)(ws);        // 12,800,000 B
    float* el      = (float*)(ws + 12800000);             //  1,600,000 B
    float* er      = (float*)(ws + 14400000);             //  1,600,000 B
    int*   totals  = (int*)  (ws + 16000000);             //  3,128 B (pad 4K)
    int*   base    = (int*)  (ws + 16004096);             //  3,132 B (pad 4K)
    int*   fcursor = (int*)  (ws + 16008192);             //  3,128 B (pad 4K)
    int*   cbase   = (int*)  (ws + 16012288);             //    396 B (pad 4K)
    int*   ccursor = (int*)  (ws + 16016384);             //    392 B (pad 4K)
    int*   node_off= (int*)  (ws + 16020480);             //    400,004 B (pad)
    uint3* wB      = (uint3*)(ws + 16424960);             // 38,400,000 B
                                                          // total ~54.8 MB
    // d_out doubles as the pass-A payload buffer (25.6 MB, exactly out_size);
    // it is fully dead before aggregate rewrites every element of rst.
    unsigned long long* wA = (unsigned long long*)d_out;

    hipMemsetAsync(totals, 0, NB * sizeof(int), stream);

    node_proj<<<1250, 256, 0, stream>>>(node_feat, Wfc, attn_l, attn_r, featb, el, er);
    bhist<<<512, 256, 0, stream>>>(dst, totals);
    bscan<<<1, 64, 0, stream>>>(totals, base, fcursor, cbase, ccursor);
    passA<<<NPA, 256, 0, stream>>>(src, dst, ccursor, wA);
    passB<<<NPB, 256, 0, stream>>>(edge_feat, We, el, er, cbase, fcursor, wA, wB);
    finesort<<<NB, 256, 0, stream>>>(base, wB, node_off);
    aggregate<<<(N_NODES * 64 + 255) / 256, 256, 0, stream>>>(node_off, wB, featb, rst);
}